// Round 3
// baseline (2773.112 us; speedup 1.0000x reference)
//
#include <hip/hip_runtime.h>
#include <stdint.h>

// ---------------------------------------------------------------------------
// DecoderRnn: 2-layer LSTM (B=32, H=512) over T=64 steps + vocab softmax (V=32000)
//   K4 k_serial round-4 changes:
//   (a) register-blocked GEMV: thread = (8 K-slices x 2 cols x 4 b-pairs);
//       each thread computes 4 gates x 2 b rows for its column. Per iter:
//       4 w + 2 h ds_read_b128 -> 32 FMA (0.33 FMA/B vs 0.125 before).
//       ds_read per wave per step: 768 -> 288. LDS return BW was the
//       bottleneck (~11 us/step of 20.5). Gate exchange eliminated (all 4
//       gates in-lane); K-reduce = 3 shfl_xor rounds over 8 slices.
//   (b) barrier counter distributed over 8 cache lines (atomicAdd to line
//       w&7; 8 lanes of wave 0 poll + shuffle-sum) -> 32-deep atomic
//       serialization instead of 256-deep.
//   (c) __launch_bounds__(256,1): 1 wave/EU is the real occupancy; give the
//       register allocator the full budget.
//   Barrier semantics unchanged from round 2/3 (relaxed post after
//   __syncthreads vmcnt-drain; relaxed polls; no wbl2/inv).
// ---------------------------------------------------------------------------

constexpr int kH = 512;
constexpr int kB = 32;
constexpr int kT = 64;
constexpr int kV = 32000;
constexpr int kG = 2048;   // 4*kH gates
constexpr int kNWG = 256;  // serial-kernel workgroups (1 per CU)
constexpr int kWS = 129;   // weight LDS row stride in f4 (516 floats = +16B pad)

typedef __attribute__((ext_vector_type(4))) float f4;
typedef __attribute__((ext_vector_type(8))) short short8;
typedef unsigned long long u64;

struct us4 { unsigned short x, y, z, w; };

__device__ inline unsigned short f2bf(float x) {
  union { float f; unsigned u; } c; c.f = x;
  unsigned r = c.u + 0x7fffu + ((c.u >> 16) & 1u);   // RNE to bf16
  return (unsigned short)(r >> 16);
}
__device__ inline float sigm(float x) { return 1.0f / (1.0f + expf(-x)); }

// ---------------------------------------------------------------------- K1
__global__ void k_init(float* __restrict__ buf2, float* __restrict__ rowsum,
                       int* __restrict__ flags /* 512 ints */) {
  int id = blockIdx.x * 256 + threadIdx.x;
  f4 z = {0.f, 0.f, 0.f, 0.f};
  if (id < 8192) ((f4*)buf2)[id] = z;       // both h2 buffers = 0
  if (id < 2048) rowsum[id] = 0.f;
  if (id < 512)  flags[id] = 0;
}

// ---------------------------------------------------------------------- K2
__global__ void k_wcvt(const float* __restrict__ W, unsigned short* __restrict__ Wu) {
  const int total = kV * kH / 4;
  for (int i = blockIdx.x * blockDim.x + threadIdx.x; i < total;
       i += gridDim.x * blockDim.x) {
    f4 v = ((const f4*)W)[i];
    us4 o = {f2bf(v.x), f2bf(v.y), f2bf(v.z), f2bf(v.w)};
    ((us4*)Wu)[i] = o;
  }
}

// ---------------------------------------------------------------------- K3
__global__ __launch_bounds__(256) void k_xg1(
    const int* __restrict__ inputs, const int* __restrict__ tseq,
    const float* __restrict__ emb, const float* __restrict__ Wih1,
    const float* __restrict__ bih1, const float* __restrict__ bhh1,
    float* __restrict__ Xg1T) {
  __shared__ float Xs[kB * kH];   // 64 KiB
  int tid = threadIdx.x;
  int t = blockIdx.x, jb = blockIdx.y;
  for (int i = tid; i < kB * kH / 4; i += 256) {
    int b = i >> 7;
    int tok = (t == 0) ? inputs[b] : tseq[b * kT + (t - 1)];
    ((f4*)Xs)[i] = ((const f4*)(emb + (size_t)tok * kH))[i & 127];
  }
  __syncthreads();
  int j2 = tid & 31, bq = tid >> 5;
  int j0 = jb * 64 + j2 * 2;
  int b0 = bq * 4;
  const f4* w0 = (const f4*)(Wih1 + (size_t)j0 * kH);
  const f4* w1 = (const f4*)(Wih1 + (size_t)(j0 + 1) * kH);
  float acc0[4] = {0.f, 0.f, 0.f, 0.f};
  float acc1[4] = {0.f, 0.f, 0.f, 0.f};
  #pragma unroll 2
  for (int k4 = 0; k4 < 128; ++k4) {
    f4 a0 = w0[k4], a1 = w1[k4];
    #pragma unroll
    for (int bb = 0; bb < 4; ++bb) {
      f4 x = ((const f4*)Xs)[(b0 + bb) * 128 + k4];
      acc0[bb] += a0.x * x.x + a0.y * x.y + a0.z * x.z + a0.w * x.w;
      acc1[bb] += a1.x * x.x + a1.y * x.y + a1.z * x.z + a1.w * x.w;
    }
  }
  float bj0 = bih1[j0] + bhh1[j0];
  float bj1 = bih1[j0 + 1] + bhh1[j0 + 1];
  f4 s0 = {acc0[0] + bj0, acc0[1] + bj0, acc0[2] + bj0, acc0[3] + bj0};
  f4 s1 = {acc1[0] + bj1, acc1[1] + bj1, acc1[2] + bj1, acc1[3] + bj1};
  float* o = Xg1T + ((size_t)t * kG + j0) * kB + b0;
  *(f4*)o = s0;
  *(f4*)(o + kB) = s1;
}

// ---------------------------------------------------------------------- K4
// Counter barrier, distributed over 8 lines (128 B apart). Producer:
// __syncthreads drains vmcnt(0) in every wave before thread 0 does one
// relaxed agent atomicAdd on line (w&7). Consumer: 8 lanes of wave 0 load
// the 8 lines, shuffle-sum, compare; then __syncthreads.
__device__ inline void postc(int* cnt) {
  __syncthreads();
  if (threadIdx.x == 0)
    __hip_atomic_fetch_add(&cnt[(blockIdx.x & 7) << 5], 1, __ATOMIC_RELAXED,
                           __HIP_MEMORY_SCOPE_AGENT);
}
__device__ inline void waitc(int* cnt, int target) {
  if (threadIdx.x < 64) {
    int lane = threadIdx.x;
    for (;;) {
      int v = (lane < 8)
                  ? __hip_atomic_load(&cnt[lane << 5], __ATOMIC_RELAXED,
                                      __HIP_MEMORY_SCOPE_AGENT)
                  : 0;
      v += __shfl_xor(v, 1);
      v += __shfl_xor(v, 2);
      v += __shfl_xor(v, 4);
      if (__shfl(v, 0) >= target) break;
      __builtin_amdgcn_s_sleep(2);
    }
  }
  __syncthreads();
}

// Stage 32x512 f32 h-state into LDS (f4 XOR-swizzle). Coherent variant uses
// relaxed agent u64 loads (bypasses stale L1 / non-coherent per-XCD L2).
__device__ inline void stage_coh(float* __restrict__ smem, const float* src) {
  const u64* s8 = (const u64*)src;
  #pragma unroll
  for (int i = 0; i < 16; ++i) {
    int idx = threadIdx.x + (i << 8);          // f4 index 0..4095
    u64 lo = __hip_atomic_load((u64*)&s8[idx * 2], __ATOMIC_RELAXED,
                               __HIP_MEMORY_SCOPE_AGENT);
    u64 hi = __hip_atomic_load((u64*)&s8[idx * 2 + 1], __ATOMIC_RELAXED,
                               __HIP_MEMORY_SCOPE_AGENT);
    int b_ = idx >> 7, k4 = idx & 127;
    union { u64 u[2]; f4 v; } cv; cv.u[0] = lo; cv.u[1] = hi;
    ((f4*)smem)[(b_ << 7) + (k4 ^ (b_ & 7))] = cv.v;
  }
}
__device__ inline void stage_plain(float* __restrict__ smem,
                                   const float* __restrict__ src) {
  const f4* s4 = (const f4*)src;
  #pragma unroll
  for (int i = 0; i < 16; ++i) {
    int idx = threadIdx.x + (i << 8);
    int b_ = idx >> 7, k4 = idx & 127;
    ((f4*)smem)[(b_ << 7) + (k4 ^ (b_ & 7))] = s4[idx];
  }
}

__device__ inline float redk(float s) {   // sum over 8 K-slice lanes
  s += __shfl_xor(s, 1);
  s += __shfl_xor(s, 2);
  s += __shfl_xor(s, 4);
  return s;
}

__global__ __launch_bounds__(256, 1) void k_serial(
    const float* __restrict__ hiddens, const float* __restrict__ Xg1T,
    const float* __restrict__ Whh1, const float* __restrict__ Wih2,
    const float* __restrict__ Whh2, const float* __restrict__ bih2,
    const float* __restrict__ bhh2,
    float* __restrict__ buf1, float* __restrict__ buf2,
    unsigned short* __restrict__ H2u, float* __restrict__ outTail,
    int* __restrict__ cntA, int* __restrict__ cntB) {
  __shared__ float smemh[kB * kH];     // 64 KiB h-state stage
  __shared__ float wlds[24 * 4 * kWS]; // 48.4 KiB weights: rows m*8 + (2*gg+nl)
  const int tid = threadIdx.x, w = blockIdx.x;
  const int lane = tid & 63, wv = tid >> 6;
  const int ks = lane & 7;             // K-slice 0..7 (16 f4 each)
  const int nl = (lane >> 3) & 1;      // column select: n = 2w + nl
  const int bq = lane >> 4;            // 0..3
  const int bp = (wv << 2) | bq;       // b-pair 0..15
  const int b0 = bp << 1, b1 = b0 + 1;
  const int b0off = b0 << 7, b1off = b1 << 7;
  const int b0sw = b0 & 7, b1sw = b1 & 7;
  const int kbase = ks << 4;           // K-slice start (f4 units)
  const int n = (w << 1) + nl;         // my hidden column

  // ---- preload this WG's 24 weight rows into LDS (row = m*8 + jj,
  //      jj = 2*gg + nl; m=0:Whh1, 1:Whh2, 2:Wih2), stride kWS f4 ----
  {
    f4* wl = (f4*)wlds;
    #pragma unroll
    for (int i = 0; i < 12; ++i) {
      int idx = tid + (i << 8);                // 0..3071
      int row = idx >> 7, k4 = idx & 127;
      int m = row >> 3, jjr = row & 7;
      int jr = ((jjr >> 1) << 9) + (w << 1) + (jjr & 1);
      const float* src = (m == 0) ? Whh1 : (m == 1) ? Whh2 : Wih2;
      wl[row * kWS + k4] = ((const f4*)(src + (size_t)jr * kH))[k4];
    }
  }
  const f4* wr_hh1[4];
  const f4* wr_hh2[4];
  const f4* wr_ih2[4];
  #pragma unroll
  for (int gg = 0; gg < 4; ++gg) {
    int row = 2 * gg + nl;
    wr_hh1[gg] = (const f4*)wlds + (0 * 8 + row) * kWS;
    wr_hh2[gg] = (const f4*)wlds + (1 * 8 + row) * kWS;
    wr_ih2[gg] = (const f4*)wlds + (2 * 8 + row) * kWS;
  }
  float bj[4];
  #pragma unroll
  for (int gg = 0; gg < 4; ++gg)
    bj[gg] = bih2[(gg << 9) + n] + bhh2[(gg << 9) + n];

  const f4* hsm = (const f4*)smemh;
  float c1a = 0.f, c1b = 0.f, c2a = 0.f, c2b = 0.f;
  const f4 z4 = {0.f, 0.f, 0.f, 0.f};

  stage_plain(smemh, hiddens);      // h1[-1]
  __syncthreads();
  for (int t = 0; t < kT; ++t) {
    float* h1w = buf1 + (t & 1) * 16384;
    float* h2w = buf2 + (t & 1) * 16384;
    const float* h2r = buf2 + ((t + 1) & 1) * 16384;   // h2[t-1]

    // prefetch x-gate terms (incl. layer-1 biases) for my (n, b0/b1)
    union { u64 u; float f[2]; } xv[4];
    const float* xbase = Xg1T + ((size_t)t * kG + n) * kB + b0;
    #pragma unroll
    for (int gg = 0; gg < 4; ++gg)
      xv[gg].u = *(const u64*)(xbase + (size_t)(gg << 9) * kB);

    // ---- layer-1: Whh1 . h1[t-1] over my K-slice, 4 gates x 2 b ----
    f4 a00 = z4, a01 = z4, a10 = z4, a11 = z4, a20 = z4, a21 = z4,
       a30 = z4, a31 = z4;
    #pragma unroll 4
    for (int kk = 0; kk < 16; ++kk) {
      int k4 = kbase + kk;
      f4 h0v = hsm[b0off + (k4 ^ b0sw)];
      f4 h1v = hsm[b1off + (k4 ^ b1sw)];
      f4 w0 = wr_hh1[0][k4], w1 = wr_hh1[1][k4];
      f4 w2 = wr_hh1[2][k4], w3 = wr_hh1[3][k4];
      a00 += w0 * h0v; a01 += w0 * h1v;
      a10 += w1 * h0v; a11 += w1 * h1v;
      a20 += w2 * h0v; a21 += w2 * h1v;
      a30 += w3 * h0v; a31 += w3 * h1v;
    }
    float G00 = redk(a00.x + a00.y + a00.z + a00.w) + xv[0].f[0];
    float G01 = redk(a01.x + a01.y + a01.z + a01.w) + xv[0].f[1];
    float G10 = redk(a10.x + a10.y + a10.z + a10.w) + xv[1].f[0];
    float G11 = redk(a11.x + a11.y + a11.z + a11.w) + xv[1].f[1];
    float G20 = redk(a20.x + a20.y + a20.z + a20.w) + xv[2].f[0];
    float G21 = redk(a21.x + a21.y + a21.z + a21.w) + xv[2].f[1];
    float G30 = redk(a30.x + a30.y + a30.z + a30.w) + xv[3].f[0];
    float G31 = redk(a31.x + a31.y + a31.z + a31.w) + xv[3].f[1];
    c1a = sigm(G10) * c1a + sigm(G00) * tanhf(G20);
    float hn0 = sigm(G30) * tanhf(c1a);
    c1b = sigm(G11) * c1b + sigm(G01) * tanhf(G21);
    float hn1 = sigm(G31) * tanhf(c1b);
    float hp0 = __shfl(hn0, lane ^ 8);   // partner column's h, same b
    float hp1 = __shfl(hn1, lane ^ 8);
    if ((lane & 15) == 0) {              // nl==0 && ks==0
      union { float f[2]; u64 u; } p0, p1;
      p0.f[0] = hn0; p0.f[1] = hp0;
      p1.f[0] = hn1; p1.f[1] = hp1;
      __hip_atomic_store((u64*)(h1w + b0 * kH + 2 * w), p0.u, __ATOMIC_RELAXED,
                         __HIP_MEMORY_SCOPE_AGENT);
      __hip_atomic_store((u64*)(h1w + b1 * kH + 2 * w), p1.u, __ATOMIC_RELAXED,
                         __HIP_MEMORY_SCOPE_AGENT);
      if (t == kT - 1) {
        *(u64*)(outTail + b0 * kH + 2 * w) = p0.u;     // final h1 output
        *(u64*)(outTail + b1 * kH + 2 * w) = p1.u;
      }
    }
    postc(cntA);                    // publish h1[t]
    waitc(cntB, 256 * t);           // h2[t-1] visible from all WGs

    stage_coh(smemh, h2r);          // h2[t-1]
    __syncthreads();
    // ---- layer-2 partial: Whh2 . h2[t-1] (overlaps other WGs' A-posts) ----
    a00 = z4; a01 = z4; a10 = z4; a11 = z4;
    a20 = z4; a21 = z4; a30 = z4; a31 = z4;
    #pragma unroll 4
    for (int kk = 0; kk < 16; ++kk) {
      int k4 = kbase + kk;
      f4 h0v = hsm[b0off + (k4 ^ b0sw)];
      f4 h1v = hsm[b1off + (k4 ^ b1sw)];
      f4 w0 = wr_hh2[0][k4], w1 = wr_hh2[1][k4];
      f4 w2 = wr_hh2[2][k4], w3 = wr_hh2[3][k4];
      a00 += w0 * h0v; a01 += w0 * h1v;
      a10 += w1 * h0v; a11 += w1 * h1v;
      a20 += w2 * h0v; a21 += w2 * h1v;
      a30 += w3 * h0v; a31 += w3 * h1v;
    }
    waitc(cntA, 256 * (t + 1));     // h1[t] visible from all WGs

    stage_coh(smemh, h1w);          // h1[t] (stays staged for next layer-1)
    __syncthreads();
    #pragma unroll 4
    for (int kk = 0; kk < 16; ++kk) {
      int k4 = kbase + kk;
      f4 h0v = hsm[b0off + (k4 ^ b0sw)];
      f4 h1v = hsm[b1off + (k4 ^ b1sw)];
      f4 w0 = wr_ih2[0][k4], w1 = wr_ih2[1][k4];
      f4 w2 = wr_ih2[2][k4], w3 = wr_ih2[3][k4];
      a00 += w0 * h0v; a01 += w0 * h1v;
      a10 += w1 * h0v; a11 += w1 * h1v;
      a20 += w2 * h0v; a21 += w2 * h1v;
      a30 += w3 * h0v; a31 += w3 * h1v;
    }
    G00 = redk(a00.x + a00.y + a00.z + a00.w) + bj[0];
    G01 = redk(a01.x + a01.y + a01.z + a01.w) + bj[0];
    G10 = redk(a10.x + a10.y + a10.z + a10.w) + bj[1];
    G11 = redk(a11.x + a11.y + a11.z + a11.w) + bj[1];
    G20 = redk(a20.x + a20.y + a20.z + a20.w) + bj[2];
    G21 = redk(a21.x + a21.y + a21.z + a21.w) + bj[2];
    G30 = redk(a30.x + a30.y + a30.z + a30.w) + bj[3];
    G31 = redk(a31.x + a31.y + a31.z + a31.w) + bj[3];
    c2a = sigm(G10) * c2a + sigm(G00) * tanhf(G20);
    float h2n0 = sigm(G30) * tanhf(c2a);
    c2b = sigm(G11) * c2b + sigm(G01) * tanhf(G21);
    float h2n1 = sigm(G31) * tanhf(c2b);
    float h2p0 = __shfl(h2n0, lane ^ 8);
    float h2p1 = __shfl(h2n1, lane ^ 8);
    if ((lane & 15) == 0) {              // nl==0 && ks==0
      union { float f[2]; u64 u; } p0, p1;
      p0.f[0] = h2n0; p0.f[1] = h2p0;
      p1.f[0] = h2n1; p1.f[1] = h2p1;
      __hip_atomic_store((u64*)(h2w + b0 * kH + 2 * w), p0.u, __ATOMIC_RELAXED,
                         __HIP_MEMORY_SCOPE_AGENT);
      __hip_atomic_store((u64*)(h2w + b1 * kH + 2 * w), p1.u, __ATOMIC_RELAXED,
                         __HIP_MEMORY_SCOPE_AGENT);
      unsigned bf0 = ((unsigned)f2bf(h2p0) << 16) | f2bf(h2n0);
      unsigned bf1 = ((unsigned)f2bf(h2p1) << 16) | f2bf(h2n1);
      *(unsigned*)(H2u + ((size_t)t * kB + b0) * kH + 2 * w) = bf0;
      *(unsigned*)(H2u + ((size_t)t * kB + b1) * kH + 2 * w) = bf1;
    }
    postc(cntB);                    // publish h2[t]
    // smemh still holds h1[t] -> next iteration's layer-1 needs no restage
  }
}

// ---------------------------------------------------------------------- K5
__global__ __launch_bounds__(256) void k_vocab(
    const unsigned short* __restrict__ H2u, const unsigned short* __restrict__ Wu,
    const float* __restrict__ bout, float* __restrict__ out,
    float* __restrict__ rowsum) {
  const int lane = threadIdx.x & 63, wv = threadIdx.x >> 6;
  const int wm = wv >> 1, wn = wv & 1;
  const int r16 = lane & 15, quad = lane >> 4;
  const int mBase = blockIdx.y * 128 + wm * 64;
  const int nBase = blockIdx.x * 128 + wn * 64;
  f4 acc[4][4];
  #pragma unroll
  for (int a = 0; a < 4; ++a)
    #pragma unroll
    for (int c = 0; c < 4; ++c) acc[a][c] = (f4){0.f, 0.f, 0.f, 0.f};
  for (int kb = 0; kb < 16; ++kb) {
    int k0 = kb * 32 + quad * 8;
    short8 af[4], bf[4];
    #pragma unroll
    for (int mt = 0; mt < 4; ++mt)
      af[mt] = *(const short8*)(H2u + (size_t)(mBase + mt * 16 + r16) * kH + k0);
    #pragma unroll
    for (int nt = 0; nt < 4; ++nt)
      bf[nt] = *(const short8*)(Wu + (size_t)(nBase + nt * 16 + r16) * kH + k0);
    #pragma unroll
    for (int mt = 0; mt < 4; ++mt)
      #pragma unroll
      for (int nt = 0; nt < 4; ++nt)
        acc[mt][nt] = __builtin_amdgcn_mfma_f32_16x16x32_bf16(
            af[mt], bf[nt], acc[mt][nt], 0, 0, 0);
  }
  float bo[4];
  #pragma unroll
  for (int nt = 0; nt < 4; ++nt) bo[nt] = bout[nBase + nt * 16 + r16];
  #pragma unroll
  for (int mt = 0; mt < 4; ++mt) {
    #pragma unroll
    for (int r = 0; r < 4; ++r) {
      int row = mBase + mt * 16 + quad * 4 + r;
      float s = 0.f;
      #pragma unroll
      for (int nt = 0; nt < 4; ++nt) {
        float p = __expf(acc[mt][nt][r] + bo[nt]);
        out[(size_t)row * kV + nBase + nt * 16 + r16] = p;
        s += p;
      }
      s += __shfl_xor(s, 1);
      s += __shfl_xor(s, 2);
      s += __shfl_xor(s, 4);
      s += __shfl_xor(s, 8);
      if (r16 == 0) atomicAdd(&rowsum[row], s);
    }
  }
}

// ---------------------------------------------------------------------- K6
__global__ void k_scale(float* __restrict__ out, const float* __restrict__ rowsum) {
  const unsigned total4 = (unsigned)(kT * kB) * (kV / 4);
  unsigned stride = gridDim.x * blockDim.x;
  for (unsigned i = blockIdx.x * blockDim.x + threadIdx.x; i < total4; i += stride) {
    unsigned row = i / (kV / 4);
    float inv = 1.0f / rowsum[row];
    f4 v = ((const f4*)out)[i];
    ((f4*)out)[i] = v * inv;
  }
}

// ---------------------------------------------------------------------------
extern "C" void kernel_launch(void* const* d_in, const int* in_sizes, int n_in,
                              void* d_out, int out_size, void* d_ws, size_t ws_size,
                              hipStream_t stream) {
  (void)in_sizes; (void)n_in; (void)out_size; (void)ws_size;
  const int*   inputs  = (const int*)d_in[0];
  const float* hiddens = (const float*)d_in[1];
  const int*   tseq    = (const int*)d_in[2];
  const float* emb  = (const float*)d_in[4];
  const float* Wih1 = (const float*)d_in[5];
  const float* Whh1 = (const float*)d_in[6];
  const float* bih1 = (const float*)d_in[7];
  const float* bhh1 = (const float*)d_in[8];
  const float* Wih2 = (const float*)d_in[9];
  const float* Whh2 = (const float*)d_in[10];
  const float* bih2 = (const float*)d_in[11];
  const float* bhh2 = (const float*)d_in[12];
  const float* Wout = (const float*)d_in[13];
  const float* bout = (const float*)d_in[14];

  // workspace layout (float offsets); ~52 MiB
  float* ws = (float*)d_ws;
  float* Xg1T = ws;                                        //  4,194,304 f
  float* buf1 = ws + 4194304;                              //  2 x 16384 f
  float* buf2 = ws + 4227072;                              //  2 x 16384 f
  unsigned short* H2u = (unsigned short*)(ws + 4259840);   //  1,048,576 bf16
  unsigned short* Wu  = (unsigned short*)(ws + 4784128);   // 16,384,000 bf16
  float* rowsum = ws + 12976128;                           //  2048 f
  int* flags = (int*)(ws + 12978176);                      //  512 ints
  int* cntA = flags;                                       //  8 lines x 128 B
  int* cntB = flags + 256;                                 //  8 lines x 128 B

  float* out = (float*)d_out;
  float* outTail = out + (size_t)kT * kB * kV;             // final h1 (32x512)

  hipLaunchKernelGGL(k_init, dim3(32), dim3(256), 0, stream, buf2, rowsum, flags);
  hipLaunchKernelGGL(k_wcvt, dim3(1024), dim3(256), 0, stream, Wout, Wu);
  hipLaunchKernelGGL(k_xg1, dim3(64, 32), dim3(256), 0, stream,
                     inputs, tseq, emb, Wih1, bih1, bhh1, Xg1T);
  hipLaunchKernelGGL(k_serial, dim3(kNWG), dim3(256), 0, stream,
                     hiddens, Xg1T, Whh1, Wih2, Whh2, bih2, bhh2,
                     buf1, buf2, H2u, outTail, cntA, cntB);
  hipLaunchKernelGGL(k_vocab, dim3(kV / 128, 16), dim3(256), 0, stream,
                     H2u, Wu, bout, out, rowsum);
  hipLaunchKernelGGL(k_scale, dim3(2048), dim3(256), 0, stream, out, rowsum);
}

// Round 4
// 2071.632 us; speedup vs baseline: 1.3386x; 1.3386x over previous
//
#include <hip/hip_runtime.h>
#include <stdint.h>

// ---------------------------------------------------------------------------
// DecoderRnn: 2-layer LSTM (B=32, H=512) over T=64 steps + vocab softmax (V=32000)
//   K4 k_serial round-5 change (one variable vs round 4):
//   STRIDED K-slices. Round 4's contiguous slice (k4 = ks*16 + kk) put all 8
//   ks-lanes in the SAME bank quad (ks*16 = 0 mod 8) -> 8-way conflicts on
//   every ds_read (SQ_LDS_BANK_CONFLICT 5.3e8, +477us). Now lane ks owns
//   k4 = kk*8 + ks:
//     weights: quad = (row*129 + k4) % 8 = (row + ks) % 8 -> per instruction
//       2 distinct addrs/quad x4 broadcast = 2-way = free.
//     h-state: quad = (k4 ^ (b&7)) % 8 = ks ^ 2bq -> 4-way (1.58x), the
//       floor (32 unique f4 = 512B/instr = 4 bank rows); only 1/3 of reads.
//   Register blocking kept: thread = (8 ks x 2 cols x 4 b-pairs), 4 gates x
//   2 b in-thread; 288 ds_read/wave/step vs 768 pre-blocking; K-reduce =
//   3 shfl_xor over ks-lanes (slices interleave, union still = all 128 k4).
//   Distributed 8-line counter barrier + relaxed posts/polls unchanged.
// ---------------------------------------------------------------------------

constexpr int kH = 512;
constexpr int kB = 32;
constexpr int kT = 64;
constexpr int kV = 32000;
constexpr int kG = 2048;   // 4*kH gates
constexpr int kNWG = 256;  // serial-kernel workgroups (1 per CU)
constexpr int kWS = 129;   // weight LDS row stride in f4 (516 floats = +16B pad)

typedef __attribute__((ext_vector_type(4))) float f4;
typedef __attribute__((ext_vector_type(8))) short short8;
typedef unsigned long long u64;

struct us4 { unsigned short x, y, z, w; };

__device__ inline unsigned short f2bf(float x) {
  union { float f; unsigned u; } c; c.f = x;
  unsigned r = c.u + 0x7fffu + ((c.u >> 16) & 1u);   // RNE to bf16
  return (unsigned short)(r >> 16);
}
__device__ inline float sigm(float x) { return 1.0f / (1.0f + expf(-x)); }

// ---------------------------------------------------------------------- K1
__global__ void k_init(float* __restrict__ buf2, float* __restrict__ rowsum,
                       int* __restrict__ flags /* 512 ints */) {
  int id = blockIdx.x * 256 + threadIdx.x;
  f4 z = {0.f, 0.f, 0.f, 0.f};
  if (id < 8192) ((f4*)buf2)[id] = z;       // both h2 buffers = 0
  if (id < 2048) rowsum[id] = 0.f;
  if (id < 512)  flags[id] = 0;
}

// ---------------------------------------------------------------------- K2
__global__ void k_wcvt(const float* __restrict__ W, unsigned short* __restrict__ Wu) {
  const int total = kV * kH / 4;
  for (int i = blockIdx.x * blockDim.x + threadIdx.x; i < total;
       i += gridDim.x * blockDim.x) {
    f4 v = ((const f4*)W)[i];
    us4 o = {f2bf(v.x), f2bf(v.y), f2bf(v.z), f2bf(v.w)};
    ((us4*)Wu)[i] = o;
  }
}

// ---------------------------------------------------------------------- K3
__global__ __launch_bounds__(256) void k_xg1(
    const int* __restrict__ inputs, const int* __restrict__ tseq,
    const float* __restrict__ emb, const float* __restrict__ Wih1,
    const float* __restrict__ bih1, const float* __restrict__ bhh1,
    float* __restrict__ Xg1T) {
  __shared__ float Xs[kB * kH];   // 64 KiB
  int tid = threadIdx.x;
  int t = blockIdx.x, jb = blockIdx.y;
  for (int i = tid; i < kB * kH / 4; i += 256) {
    int b = i >> 7;
    int tok = (t == 0) ? inputs[b] : tseq[b * kT + (t - 1)];
    ((f4*)Xs)[i] = ((const f4*)(emb + (size_t)tok * kH))[i & 127];
  }
  __syncthreads();
  int j2 = tid & 31, bq = tid >> 5;
  int j0 = jb * 64 + j2 * 2;
  int b0 = bq * 4;
  const f4* w0 = (const f4*)(Wih1 + (size_t)j0 * kH);
  const f4* w1 = (const f4*)(Wih1 + (size_t)(j0 + 1) * kH);
  float acc0[4] = {0.f, 0.f, 0.f, 0.f};
  float acc1[4] = {0.f, 0.f, 0.f, 0.f};
  #pragma unroll 2
  for (int k4 = 0; k4 < 128; ++k4) {
    f4 a0 = w0[k4], a1 = w1[k4];
    #pragma unroll
    for (int bb = 0; bb < 4; ++bb) {
      f4 x = ((const f4*)Xs)[(b0 + bb) * 128 + k4];
      acc0[bb] += a0.x * x.x + a0.y * x.y + a0.z * x.z + a0.w * x.w;
      acc1[bb] += a1.x * x.x + a1.y * x.y + a1.z * x.z + a1.w * x.w;
    }
  }
  float bj0 = bih1[j0] + bhh1[j0];
  float bj1 = bih1[j0 + 1] + bhh1[j0 + 1];
  f4 s0 = {acc0[0] + bj0, acc0[1] + bj0, acc0[2] + bj0, acc0[3] + bj0};
  f4 s1 = {acc1[0] + bj1, acc1[1] + bj1, acc1[2] + bj1, acc1[3] + bj1};
  float* o = Xg1T + ((size_t)t * kG + j0) * kB + b0;
  *(f4*)o = s0;
  *(f4*)(o + kB) = s1;
}

// ---------------------------------------------------------------------- K4
// Counter barrier, distributed over 8 lines (128 B apart). Producer:
// __syncthreads drains vmcnt(0) in every wave before thread 0 does one
// relaxed agent atomicAdd on line (w&7). Consumer: 8 lanes of wave 0 load
// the 8 lines, shuffle-sum, compare; then __syncthreads.
__device__ inline void postc(int* cnt) {
  __syncthreads();
  if (threadIdx.x == 0)
    __hip_atomic_fetch_add(&cnt[(blockIdx.x & 7) << 5], 1, __ATOMIC_RELAXED,
                           __HIP_MEMORY_SCOPE_AGENT);
}
__device__ inline void waitc(int* cnt, int target) {
  if (threadIdx.x < 64) {
    int lane = threadIdx.x;
    for (;;) {
      int v = (lane < 8)
                  ? __hip_atomic_load(&cnt[lane << 5], __ATOMIC_RELAXED,
                                      __HIP_MEMORY_SCOPE_AGENT)
                  : 0;
      v += __shfl_xor(v, 1);
      v += __shfl_xor(v, 2);
      v += __shfl_xor(v, 4);
      if (__shfl(v, 0) >= target) break;
      __builtin_amdgcn_s_sleep(2);
    }
  }
  __syncthreads();
}

// Stage 32x512 f32 h-state into LDS (f4 XOR-swizzle). Coherent variant uses
// relaxed agent u64 loads (bypasses stale L1 / non-coherent per-XCD L2).
__device__ inline void stage_coh(float* __restrict__ smem, const float* src) {
  const u64* s8 = (const u64*)src;
  #pragma unroll
  for (int i = 0; i < 16; ++i) {
    int idx = threadIdx.x + (i << 8);          // f4 index 0..4095
    u64 lo = __hip_atomic_load((u64*)&s8[idx * 2], __ATOMIC_RELAXED,
                               __HIP_MEMORY_SCOPE_AGENT);
    u64 hi = __hip_atomic_load((u64*)&s8[idx * 2 + 1], __ATOMIC_RELAXED,
                               __HIP_MEMORY_SCOPE_AGENT);
    int b_ = idx >> 7, k4 = idx & 127;
    union { u64 u[2]; f4 v; } cv; cv.u[0] = lo; cv.u[1] = hi;
    ((f4*)smem)[(b_ << 7) + (k4 ^ (b_ & 7))] = cv.v;
  }
}
__device__ inline void stage_plain(float* __restrict__ smem,
                                   const float* __restrict__ src) {
  const f4* s4 = (const f4*)src;
  #pragma unroll
  for (int i = 0; i < 16; ++i) {
    int idx = threadIdx.x + (i << 8);
    int b_ = idx >> 7, k4 = idx & 127;
    ((f4*)smem)[(b_ << 7) + (k4 ^ (b_ & 7))] = s4[idx];
  }
}

__device__ inline float redk(float s) {   // sum over 8 K-slice lanes
  s += __shfl_xor(s, 1);
  s += __shfl_xor(s, 2);
  s += __shfl_xor(s, 4);
  return s;
}

__global__ __launch_bounds__(256, 1) void k_serial(
    const float* __restrict__ hiddens, const float* __restrict__ Xg1T,
    const float* __restrict__ Whh1, const float* __restrict__ Wih2,
    const float* __restrict__ Whh2, const float* __restrict__ bih2,
    const float* __restrict__ bhh2,
    float* __restrict__ buf1, float* __restrict__ buf2,
    unsigned short* __restrict__ H2u, float* __restrict__ outTail,
    int* __restrict__ cntA, int* __restrict__ cntB) {
  __shared__ float smemh[kB * kH];     // 64 KiB h-state stage
  __shared__ float wlds[24 * 4 * kWS]; // 48.4 KiB weights: rows m*8 + (2*gg+nl)
  const int tid = threadIdx.x, w = blockIdx.x;
  const int lane = tid & 63, wv = tid >> 6;
  const int ks = lane & 7;             // K-slice 0..7, STRIDED: k4 = kk*8+ks
  const int nl = (lane >> 3) & 1;      // column select: n = 2w + nl
  const int bq = lane >> 4;            // 0..3
  const int bp = (wv << 2) | bq;       // b-pair 0..15
  const int b0 = bp << 1, b1 = b0 + 1;
  const int b0off = b0 << 7, b1off = b1 << 7;
  const int b0sw = b0 & 7, b1sw = b1 & 7;
  const int n = (w << 1) + nl;         // my hidden column

  // ---- preload this WG's 24 weight rows into LDS (row = m*8 + jj,
  //      jj = 2*gg + nl; m=0:Whh1, 1:Whh2, 2:Wih2), stride kWS f4 ----
  {
    f4* wl = (f4*)wlds;
    #pragma unroll
    for (int i = 0; i < 12; ++i) {
      int idx = tid + (i << 8);                // 0..3071
      int row = idx >> 7, k4 = idx & 127;
      int m = row >> 3, jjr = row & 7;
      int jr = ((jjr >> 1) << 9) + (w << 1) + (jjr & 1);
      const float* src = (m == 0) ? Whh1 : (m == 1) ? Whh2 : Wih2;
      wl[row * kWS + k4] = ((const f4*)(src + (size_t)jr * kH))[k4];
    }
  }
  const f4* wr_hh1[4];
  const f4* wr_hh2[4];
  const f4* wr_ih2[4];
  #pragma unroll
  for (int gg = 0; gg < 4; ++gg) {
    int row = 2 * gg + nl;
    wr_hh1[gg] = (const f4*)wlds + (0 * 8 + row) * kWS;
    wr_hh2[gg] = (const f4*)wlds + (1 * 8 + row) * kWS;
    wr_ih2[gg] = (const f4*)wlds + (2 * 8 + row) * kWS;
  }
  float bj[4];
  #pragma unroll
  for (int gg = 0; gg < 4; ++gg)
    bj[gg] = bih2[(gg << 9) + n] + bhh2[(gg << 9) + n];

  const f4* hsm = (const f4*)smemh;
  float c1a = 0.f, c1b = 0.f, c2a = 0.f, c2b = 0.f;
  const f4 z4 = {0.f, 0.f, 0.f, 0.f};

  stage_plain(smemh, hiddens);      // h1[-1]
  __syncthreads();
  for (int t = 0; t < kT; ++t) {
    float* h1w = buf1 + (t & 1) * 16384;
    float* h2w = buf2 + (t & 1) * 16384;
    const float* h2r = buf2 + ((t + 1) & 1) * 16384;   // h2[t-1]

    // prefetch x-gate terms (incl. layer-1 biases) for my (n, b0/b1)
    union { u64 u; float f[2]; } xv[4];
    const float* xbase = Xg1T + ((size_t)t * kG + n) * kB + b0;
    #pragma unroll
    for (int gg = 0; gg < 4; ++gg)
      xv[gg].u = *(const u64*)(xbase + (size_t)(gg << 9) * kB);

    // ---- layer-1: Whh1 . h1[t-1] over my strided K-slice, 4 gates x 2 b ----
    f4 a00 = z4, a01 = z4, a10 = z4, a11 = z4, a20 = z4, a21 = z4,
       a30 = z4, a31 = z4;
    #pragma unroll 4
    for (int kk = 0; kk < 16; ++kk) {
      int k4 = (kk << 3) | ks;
      f4 h0v = hsm[b0off + (k4 ^ b0sw)];
      f4 h1v = hsm[b1off + (k4 ^ b1sw)];
      f4 w0 = wr_hh1[0][k4], w1 = wr_hh1[1][k4];
      f4 w2 = wr_hh1[2][k4], w3 = wr_hh1[3][k4];
      a00 += w0 * h0v; a01 += w0 * h1v;
      a10 += w1 * h0v; a11 += w1 * h1v;
      a20 += w2 * h0v; a21 += w2 * h1v;
      a30 += w3 * h0v; a31 += w3 * h1v;
    }
    float G00 = redk(a00.x + a00.y + a00.z + a00.w) + xv[0].f[0];
    float G01 = redk(a01.x + a01.y + a01.z + a01.w) + xv[0].f[1];
    float G10 = redk(a10.x + a10.y + a10.z + a10.w) + xv[1].f[0];
    float G11 = redk(a11.x + a11.y + a11.z + a11.w) + xv[1].f[1];
    float G20 = redk(a20.x + a20.y + a20.z + a20.w) + xv[2].f[0];
    float G21 = redk(a21.x + a21.y + a21.z + a21.w) + xv[2].f[1];
    float G30 = redk(a30.x + a30.y + a30.z + a30.w) + xv[3].f[0];
    float G31 = redk(a31.x + a31.y + a31.z + a31.w) + xv[3].f[1];
    c1a = sigm(G10) * c1a + sigm(G00) * tanhf(G20);
    float hn0 = sigm(G30) * tanhf(c1a);
    c1b = sigm(G11) * c1b + sigm(G01) * tanhf(G21);
    float hn1 = sigm(G31) * tanhf(c1b);
    float hp0 = __shfl(hn0, lane ^ 8);   // partner column's h, same b
    float hp1 = __shfl(hn1, lane ^ 8);
    if ((lane & 15) == 0) {              // nl==0 && ks==0
      union { float f[2]; u64 u; } p0, p1;
      p0.f[0] = hn0; p0.f[1] = hp0;
      p1.f[0] = hn1; p1.f[1] = hp1;
      __hip_atomic_store((u64*)(h1w + b0 * kH + 2 * w), p0.u, __ATOMIC_RELAXED,
                         __HIP_MEMORY_SCOPE_AGENT);
      __hip_atomic_store((u64*)(h1w + b1 * kH + 2 * w), p1.u, __ATOMIC_RELAXED,
                         __HIP_MEMORY_SCOPE_AGENT);
      if (t == kT - 1) {
        *(u64*)(outTail + b0 * kH + 2 * w) = p0.u;     // final h1 output
        *(u64*)(outTail + b1 * kH + 2 * w) = p1.u;
      }
    }
    postc(cntA);                    // publish h1[t]
    waitc(cntB, 256 * t);           // h2[t-1] visible from all WGs

    stage_coh(smemh, h2r);          // h2[t-1]
    __syncthreads();
    // ---- layer-2 partial: Whh2 . h2[t-1] (overlaps other WGs' A-posts) ----
    a00 = z4; a01 = z4; a10 = z4; a11 = z4;
    a20 = z4; a21 = z4; a30 = z4; a31 = z4;
    #pragma unroll 4
    for (int kk = 0; kk < 16; ++kk) {
      int k4 = (kk << 3) | ks;
      f4 h0v = hsm[b0off + (k4 ^ b0sw)];
      f4 h1v = hsm[b1off + (k4 ^ b1sw)];
      f4 w0 = wr_hh2[0][k4], w1 = wr_hh2[1][k4];
      f4 w2 = wr_hh2[2][k4], w3 = wr_hh2[3][k4];
      a00 += w0 * h0v; a01 += w0 * h1v;
      a10 += w1 * h0v; a11 += w1 * h1v;
      a20 += w2 * h0v; a21 += w2 * h1v;
      a30 += w3 * h0v; a31 += w3 * h1v;
    }
    waitc(cntA, 256 * (t + 1));     // h1[t] visible from all WGs

    stage_coh(smemh, h1w);          // h1[t] (stays staged for next layer-1)
    __syncthreads();
    #pragma unroll 4
    for (int kk = 0; kk < 16; ++kk) {
      int k4 = (kk << 3) | ks;
      f4 h0v = hsm[b0off + (k4 ^ b0sw)];
      f4 h1v = hsm[b1off + (k4 ^ b1sw)];
      f4 w0 = wr_ih2[0][k4], w1 = wr_ih2[1][k4];
      f4 w2 = wr_ih2[2][k4], w3 = wr_ih2[3][k4];
      a00 += w0 * h0v; a01 += w0 * h1v;
      a10 += w1 * h0v; a11 += w1 * h1v;
      a20 += w2 * h0v; a21 += w2 * h1v;
      a30 += w3 * h0v; a31 += w3 * h1v;
    }
    G00 = redk(a00.x + a00.y + a00.z + a00.w) + bj[0];
    G01 = redk(a01.x + a01.y + a01.z + a01.w) + bj[0];
    G10 = redk(a10.x + a10.y + a10.z + a10.w) + bj[1];
    G11 = redk(a11.x + a11.y + a11.z + a11.w) + bj[1];
    G20 = redk(a20.x + a20.y + a20.z + a20.w) + bj[2];
    G21 = redk(a21.x + a21.y + a21.z + a21.w) + bj[2];
    G30 = redk(a30.x + a30.y + a30.z + a30.w) + bj[3];
    G31 = redk(a31.x + a31.y + a31.z + a31.w) + bj[3];
    c2a = sigm(G10) * c2a + sigm(G00) * tanhf(G20);
    float h2n0 = sigm(G30) * tanhf(c2a);
    c2b = sigm(G11) * c2b + sigm(G01) * tanhf(G21);
    float h2n1 = sigm(G31) * tanhf(c2b);
    float h2p0 = __shfl(h2n0, lane ^ 8);
    float h2p1 = __shfl(h2n1, lane ^ 8);
    if ((lane & 15) == 0) {              // nl==0 && ks==0
      union { float f[2]; u64 u; } p0, p1;
      p0.f[0] = h2n0; p0.f[1] = h2p0;
      p1.f[0] = h2n1; p1.f[1] = h2p1;
      __hip_atomic_store((u64*)(h2w + b0 * kH + 2 * w), p0.u, __ATOMIC_RELAXED,
                         __HIP_MEMORY_SCOPE_AGENT);
      __hip_atomic_store((u64*)(h2w + b1 * kH + 2 * w), p1.u, __ATOMIC_RELAXED,
                         __HIP_MEMORY_SCOPE_AGENT);
      unsigned bf0 = ((unsigned)f2bf(h2p0) << 16) | f2bf(h2n0);
      unsigned bf1 = ((unsigned)f2bf(h2p1) << 16) | f2bf(h2n1);
      *(unsigned*)(H2u + ((size_t)t * kB + b0) * kH + 2 * w) = bf0;
      *(unsigned*)(H2u + ((size_t)t * kB + b1) * kH + 2 * w) = bf1;
    }
    postc(cntB);                    // publish h2[t]
    // smemh still holds h1[t] -> next iteration's layer-1 needs no restage
  }
}

// ---------------------------------------------------------------------- K5
__global__ __launch_bounds__(256) void k_vocab(
    const unsigned short* __restrict__ H2u, const unsigned short* __restrict__ Wu,
    const float* __restrict__ bout, float* __restrict__ out,
    float* __restrict__ rowsum) {
  const int lane = threadIdx.x & 63, wv = threadIdx.x >> 6;
  const int wm = wv >> 1, wn = wv & 1;
  const int r16 = lane & 15, quad = lane >> 4;
  const int mBase = blockIdx.y * 128 + wm * 64;
  const int nBase = blockIdx.x * 128 + wn * 64;
  f4 acc[4][4];
  #pragma unroll
  for (int a = 0; a < 4; ++a)
    #pragma unroll
    for (int c = 0; c < 4; ++c) acc[a][c] = (f4){0.f, 0.f, 0.f, 0.f};
  for (int kb = 0; kb < 16; ++kb) {
    int k0 = kb * 32 + quad * 8;
    short8 af[4], bf[4];
    #pragma unroll
    for (int mt = 0; mt < 4; ++mt)
      af[mt] = *(const short8*)(H2u + (size_t)(mBase + mt * 16 + r16) * kH + k0);
    #pragma unroll
    for (int nt = 0; nt < 4; ++nt)
      bf[nt] = *(const short8*)(Wu + (size_t)(nBase + nt * 16 + r16) * kH + k0);
    #pragma unroll
    for (int mt = 0; mt < 4; ++mt)
      #pragma unroll
      for (int nt = 0; nt < 4; ++nt)
        acc[mt][nt] = __builtin_amdgcn_mfma_f32_16x16x32_bf16(
            af[mt], bf[nt], acc[mt][nt], 0, 0, 0);
  }
  float bo[4];
  #pragma unroll
  for (int nt = 0; nt < 4; ++nt) bo[nt] = bout[nBase + nt * 16 + r16];
  #pragma unroll
  for (int mt = 0; mt < 4; ++mt) {
    #pragma unroll
    for (int r = 0; r < 4; ++r) {
      int row = mBase + mt * 16 + quad * 4 + r;
      float s = 0.f;
      #pragma unroll
      for (int nt = 0; nt < 4; ++nt) {
        float p = __expf(acc[mt][nt][r] + bo[nt]);
        out[(size_t)row * kV + nBase + nt * 16 + r16] = p;
        s += p;
      }
      s += __shfl_xor(s, 1);
      s += __shfl_xor(s, 2);
      s += __shfl_xor(s, 4);
      s += __shfl_xor(s, 8);
      if (r16 == 0) atomicAdd(&rowsum[row], s);
    }
  }
}

// ---------------------------------------------------------------------- K6
__global__ void k_scale(float* __restrict__ out, const float* __restrict__ rowsum) {
  const unsigned total4 = (unsigned)(kT * kB) * (kV / 4);
  unsigned stride = gridDim.x * blockDim.x;
  for (unsigned i = blockIdx.x * blockDim.x + threadIdx.x; i < total4; i += stride) {
    unsigned row = i / (kV / 4);
    float inv = 1.0f / rowsum[row];
    f4 v = ((const f4*)out)[i];
    ((f4*)out)[i] = v * inv;
  }
}

// ---------------------------------------------------------------------------
extern "C" void kernel_launch(void* const* d_in, const int* in_sizes, int n_in,
                              void* d_out, int out_size, void* d_ws, size_t ws_size,
                              hipStream_t stream) {
  (void)in_sizes; (void)n_in; (void)out_size; (void)ws_size;
  const int*   inputs  = (const int*)d_in[0];
  const float* hiddens = (const float*)d_in[1];
  const int*   tseq    = (const int*)d_in[2];
  const float* emb  = (const float*)d_in[4];
  const float* Wih1 = (const float*)d_in[5];
  const float* Whh1 = (const float*)d_in[6];
  const float* bih1 = (const float*)d_in[7];
  const float* bhh1 = (const float*)d_in[8];
  const float* Wih2 = (const float*)d_in[9];
  const float* Whh2 = (const float*)d_in[10];
  const float* bih2 = (const float*)d_in[11];
  const float* bhh2 = (const float*)d_in[12];
  const float* Wout = (const float*)d_in[13];
  const float* bout = (const float*)d_in[14];

  // workspace layout (float offsets); ~52 MiB
  float* ws = (float*)d_ws;
  float* Xg1T = ws;                                        //  4,194,304 f
  float* buf1 = ws + 4194304;                              //  2 x 16384 f
  float* buf2 = ws + 4227072;                              //  2 x 16384 f
  unsigned short* H2u = (unsigned short*)(ws + 4259840);   //  1,048,576 bf16
  unsigned short* Wu  = (unsigned short*)(ws + 4784128);   // 16,384,000 bf16
  float* rowsum = ws + 12976128;                           //  2048 f
  int* flags = (int*)(ws + 12978176);                      //  512 ints
  int* cntA = flags;                                       //  8 lines x 128 B
  int* cntB = flags + 256;                                 //  8 lines x 128 B

  float* out = (float*)d_out;
  float* outTail = out + (size_t)kT * kB * kV;             // final h1 (32x512)

  hipLaunchKernelGGL(k_init, dim3(32), dim3(256), 0, stream, buf2, rowsum, flags);
  hipLaunchKernelGGL(k_wcvt, dim3(1024), dim3(256), 0, stream, Wout, Wu);
  hipLaunchKernelGGL(k_xg1, dim3(64, 32), dim3(256), 0, stream,
                     inputs, tseq, emb, Wih1, bih1, bhh1, Xg1T);
  hipLaunchKernelGGL(k_serial, dim3(kNWG), dim3(256), 0, stream,
                     hiddens, Xg1T, Whh1, Wih2, Whh2, bih2, bhh2,
                     buf1, buf2, H2u, outTail, cntA, cntB);
  hipLaunchKernelGGL(k_vocab, dim3(kV / 128, 16), dim3(256), 0, stream,
                     H2u, Wu, bout, out, rowsum);
  hipLaunchKernelGGL(k_scale, dim3(2048), dim3(256), 0, stream, out, rowsum);
}